// Round 13
// baseline (329.867 us; speedup 1.0000x reference)
//
#include <hip/hip_runtime.h>
#include <hip/hip_bf16.h>

// B=2,S=2048 -> T=4096 tokens; D=1024; N=64 experts; R=64; TOP_K=2.
// Inputs runtime-detected f32 vs bf16 (measured: f32). Outputs f32 flat:
// [0,262144) proj; [262144,270336) idx; [270336,278528) w.
// R22: R21 persistent-rw regressed (136.2). Root-cause of the 43us score
// floor identified: HIP __syncthreads drains vmcnt(0), so EVERY prefetch
// (R15/16/17/21) was force-completed ~400cy after issue at the next
// barrier vs ~900cy HBM latency -- depth never mattered. Fix (T3/T4):
// revert to the exact 123.9us R11 build; in score's K-loop only, replace
// __syncthreads with raw {s_waitcnt lgkmcnt(0); s_barrier} (LDS ordering
// kept, vmcnt NOT drained) + px 2-deep parity sets (x chunk i+2 issued at
// iter i, used at iter i+2 => ~1000cy budget >= 900cy HBM). pw 1-deep
// (L2 ~200cy, covered). Post-loop barriers standard (nothing in flight).
// topk(64x64)/egemm(2-deep)/combine byte-identical to the 123.9 build.
// Harness d_ws poison fill (~44us, evicts L3 every iter) untouchable.
// d_ws: f32 w[8192] (32KB); int cnt[64]; int list[64*1024] (256KB);
//       Sb f32[2][4096][64] @ +1MB (2MB); P f32[8192][8][64] @ +4MB (16MB).

typedef unsigned short u16;
typedef unsigned int u32;
typedef __attribute__((ext_vector_type(8))) short short8;
typedef __attribute__((ext_vector_type(4))) float f32x4;

__device__ __forceinline__ float bf2f(u16 u) {
    u32 v = ((u32)u) << 16; float f; __builtin_memcpy(&f, &v, 4); return f;
}
__device__ __forceinline__ u16 f2bf(float f) {  // RNE
    u32 u; __builtin_memcpy(&u, &f, 4);
    u32 r = u + 0x7fff + ((u >> 16) & 1);
    return (u16)(r >> 16);
}
__device__ __forceinline__ u32 pack2(float a, float b) {
    return ((u32)f2bf(b) << 16) | (u32)f2bf(a);
}

// LDS-ordering barrier WITHOUT the vmcnt(0) drain __syncthreads imposes:
// lgkmcnt(0) orders all LDS traffic; global loads stay in flight.
#define SBAR_LDS()                                              \
    do {                                                        \
        asm volatile("s_waitcnt lgkmcnt(0)" ::: "memory");      \
        __builtin_amdgcn_s_barrier();                           \
    } while (0)

#define T_TOKENS 4096
#define DDIM 1024
#define NEXP 64
#define RDIM 64
#define LCAP 1024
#define OUT_IDX_OFF 262144
#define OUT_W_OFF 270336

struct LdBF {
    const u16* p;
    __device__ __forceinline__ float4 ld4(size_t i) const {
        ushort4 v = *(const ushort4*)(p + i);
        return make_float4(bf2f(v.x), bf2f(v.y), bf2f(v.z), bf2f(v.w));
    }
    __device__ __forceinline__ float ld1(size_t i) const { return bf2f(p[i]); }
};
struct LdF32 {
    const float* p;
    __device__ __forceinline__ float4 ld4(size_t i) const { return *(const float4*)(p + i); }
    __device__ __forceinline__ float ld1(size_t i) const { return p[i]; }
};

// in-block dtype probe: 1 if f32, 0 if bf16 (all blocks same verdict).
__device__ __forceinline__ int detect_f32(const u16* x, int* lds_cnt) {
    if (threadIdx.x == 0) *lds_cnt = 0;
    __syncthreads();
    if (threadIdx.x < 256) {
        unsigned e = (x[threadIdx.x] >> 7) & 0xFF;
        if (e >= 0x68 && e <= 0x88) atomicAdd(lds_cnt, 1);
    }
    __syncthreads();
    int f = (*lds_cnt < 200) ? 1 : 0;
    __syncthreads();
    return f;
}

// ---------------- Kernel A: score GEMM partials (K-split) ------------------
// 1024 blocks x 256 thr: g=bid>>1 (tokens [8g,8g+8)), kh=bid&1 (k half
// [512kh,512kh+512)). 8 K-chunks of 64, order rotated by bid&7. R14-proven
// M4xE8 compute core. K-loop barriers are raw lgkmcnt-only (SBAR_LDS) so
// global prefetches survive barriers; px 2-deep parity (chunk i+2 issued
// at iter i), pw 1-deep. Fully unrolled => static px set selection.
// Partial scores -> Sb[kh*4096 + t][e]; top2 in its own kernel.
template <class LD>
__device__ __forceinline__ void score_body(LD xld, LD rwld,
                                           float* xs /*8*68*/, float* wt /*64*68*/,
                                           float* sc /*8*65*/, float* Sb) {
    const int tid = threadIdx.x;
    const int g = blockIdx.x >> 1;
    const int kh = blockIdx.x & 1;
    const size_t t0 = (size_t)g * 8;
    const int kbase = kh * 512;
    const int wv = tid >> 6;
    const int lane = tid & 63;
    const int tg = lane & 1;
    const int eg = (lane >> 1) & 7;
    const int kql = (lane >> 4) & 3;
    const int dd = 4 * kql + 16 * wv;
    const int kc0 = blockIdx.x & 7;    // rotated chunk start (8 chunks)

    const int sm = tid >> 4;            // staging roles (coalesced)
    const int sd4 = (tid & 15) * 4;

    float acc[4][8];
#pragma unroll
    for (int mi = 0; mi < 4; ++mi)
#pragma unroll
        for (int ei = 0; ei < 8; ++ei) acc[mi][ei] = 0.f;

#define KCH(i) (kbase + (((i) + kc0) & 7) * 64)

    // prologue: px 2-deep (chunks 0,1), pw 1-deep (chunk 0)
    float4 px0, px1;
    if (tid < 128) {
        px0 = xld.ld4((t0 + sm) * DDIM + KCH(0) + sd4);
        px1 = xld.ld4((t0 + sm) * DDIM + KCH(1) + sd4);
    }
    float4 pw[4];
#pragma unroll
    for (int h = 0; h < 4; ++h) {
        int i4 = tid + h * 256;
        pw[h] = rwld.ld4((size_t)(i4 >> 4) * DDIM + KCH(0) + (i4 & 15) * 4);
    }

#pragma unroll
    for (int i = 0; i < 8; ++i) {
        if (i > 0) SBAR_LDS();                   // prior chunk's LDS reads done
        if (tid < 128) *(float4*)&xs[sm * 68 + sd4] = ((i & 1) ? px1 : px0);
#pragma unroll
        for (int h = 0; h < 4; ++h) {
            int i4 = tid + h * 256;
            *(float4*)&wt[(i4 >> 4) * 68 + (i4 & 15) * 4] = pw[h];
        }
        SBAR_LDS();                              // staged data visible

        if (i < 6 && tid < 128) {                // refill consumed px set w/ chunk i+2
            float4 v = xld.ld4((t0 + sm) * DDIM + KCH(i + 2) + sd4);
            if (i & 1) px1 = v; else px0 = v;
        }
        if (i < 7) {                             // pw 1-deep (L2-resident rw)
#pragma unroll
            for (int h = 0; h < 4; ++h) {
                int i4 = tid + h * 256;
                pw[h] = rwld.ld4((size_t)(i4 >> 4) * DDIM + KCH(i + 1) + (i4 & 15) * 4);
            }
        }

        float4 xv[4], wv4[8];
#pragma unroll
        for (int mi = 0; mi < 4; ++mi)
            xv[mi] = *(const float4*)&xs[(tg + 2 * mi) * 68 + dd];
#pragma unroll
        for (int ei = 0; ei < 8; ++ei)
            wv4[ei] = *(const float4*)&wt[(eg + 8 * ei) * 68 + dd];
#pragma unroll
        for (int mi = 0; mi < 4; ++mi)
#pragma unroll
            for (int ei = 0; ei < 8; ++ei)
                acc[mi][ei] += xv[mi].x * wv4[ei].x + xv[mi].y * wv4[ei].y +
                               xv[mi].z * wv4[ei].z + xv[mi].w * wv4[ei].w;
    }
#undef KCH

    // in-wave k-quad reduce (deterministic tree over kql)
#pragma unroll
    for (int mi = 0; mi < 4; ++mi)
#pragma unroll
        for (int ei = 0; ei < 8; ++ei) {
            float v = acc[mi][ei];
            v += __shfl_xor(v, 16, 64);
            v += __shfl_xor(v, 32, 64);
            acc[mi][ei] = v;
        }
    __syncthreads();   // nothing left in flight; full drain harmless here

    // cross-wave reduce: sequential wave phases (deterministic order)
    for (int w = 0; w < 4; ++w) {
        if (wv == w && kql == 0) {
#pragma unroll
            for (int mi = 0; mi < 4; ++mi)
#pragma unroll
                for (int ei = 0; ei < 8; ++ei) {
                    int idx = (tg + 2 * mi) * 65 + eg + 8 * ei;
                    sc[idx] = (w == 0) ? acc[mi][ei] : sc[idx] + acc[mi][ei];
                }
        }
        __syncthreads();
    }

    // store this K-half's partial scores: 8 tokens x 64 experts
    if (tid < 128) {
        int t = tid >> 4, e4 = (tid & 15) * 4;
        const float* s = &sc[t * 65 + e4];
        float4 v = make_float4(s[0], s[1], s[2], s[3]);
        *(float4*)&Sb[((size_t)kh * T_TOKENS + t0 + t) * 64 + e4] = v;
    }
}

__global__ __launch_bounds__(256, 4) void score_part(const void* x, const void* rw,
                                                     float* Sb) {
    __shared__ float xs[8 * 68];
    __shared__ float wt[64 * 68];
    __shared__ float sc[8 * 65];
    __shared__ int dc;
    int f = detect_f32((const u16*)x, &dc);
    if (f)
        score_body(LdF32{(const float*)x}, LdF32{(const float*)rw}, xs, wt, sc, Sb);
    else
        score_body(LdBF{(const u16*)x}, LdBF{(const u16*)rw}, xs, wt, sc, Sb);
}

// ---------------- Kernel A2: top-2 + softmax + outputs + expert lists -----
// 64 blocks x 64 thr; 1 token/thread. score[t][e] = Sb[0][t][e]+Sb[1][t][e]
// (2-addend fl-sum: order-independent => deterministic). Same scan/tie-break
// semantics as reference (strict >, ascending j).
__global__ __launch_bounds__(64) void topk_softmax(const float* Sb, float* out,
                                                   float* wsW, int* wsCnt,
                                                   int* wsList) {
    int t = blockIdx.x * 64 + threadIdx.x;       // [0, 4096)
    const float* s0 = Sb + (size_t)t * 64;
    const float* s1 = Sb + ((size_t)T_TOKENS + t) * 64;
    float best = -1e30f, secv = -1e30f;
    int bi = 0, si = 0;
    for (int j = 0; j < NEXP; j += 4) {
        float4 a = *(const float4*)(s0 + j);
        float4 b = *(const float4*)(s1 + j);
        float v0 = a.x + b.x, v1 = a.y + b.y, v2 = a.z + b.z, v3 = a.w + b.w;
        if (v0 > best) { secv = best; si = bi; best = v0; bi = j; }
        else if (v0 > secv) { secv = v0; si = j; }
        if (v1 > best) { secv = best; si = bi; best = v1; bi = j + 1; }
        else if (v1 > secv) { secv = v1; si = j + 1; }
        if (v2 > best) { secv = best; si = bi; best = v2; bi = j + 2; }
        else if (v2 > secv) { secv = v2; si = j + 2; }
        if (v3 > best) { secv = best; si = bi; best = v3; bi = j + 3; }
        else if (v3 > secv) { secv = v3; si = j + 3; }
    }
    float w0 = 1.0f / (1.0f + expf(secv - best));
    float w1 = 1.0f - w0;
    out[OUT_IDX_OFF + (size_t)t * 2 + 0] = (float)bi;
    out[OUT_IDX_OFF + (size_t)t * 2 + 1] = (float)si;
    out[OUT_W_OFF + (size_t)t * 2 + 0] = w0;
    out[OUT_W_OFF + (size_t)t * 2 + 1] = w1;
    wsW[t * 2 + 0] = w0;
    wsW[t * 2 + 1] = w1;
    int p0 = atomicAdd(&wsCnt[bi], 1);
    if (p0 < LCAP) wsList[bi * LCAP + p0] = t * 2 + 0;
    int p1 = atomicAdd(&wsCnt[si], 1);
    if (p1 < LCAP) wsList[si * LCAP + p1] = t * 2 + 1;
}

// ---------------- Kernel B: per-expert bf16 MFMA GEMM, K-eighth persist-B --
// 512 blocks: e = bid>>3, oct = bid&7; k window [oct*128, oct*128+128).
// Stage B eighth ONCE; preload expert token list to LDS. Tile loop:
// 2-deep A-prefetch (named reg sets + swap), 4 MFMA, plain stores of raw
// partials to P[t2*512 + oct*64 + col]. No atomics.
template <class LD>
__device__ __forceinline__ void egemm_body(LD xld, LD nld,
                                           const int* wsCnt, const int* wsList,
                                           float* P,
                                           u16* Ab /*16*136*/, u16* Bb /*64*136*/,
                                           int* eL /*1024*/) {
    const int tid = threadIdx.x;
    const int e = blockIdx.x >> 3;
    const int oct = blockIdx.x & 7;
    const int cntE = min(wsCnt[e], LCAP);
    if (cntE <= 0) return;                       // uniform exit
    const int wv = tid >> 6;
    const int lane = tid & 63;
    const int l15 = lane & 15, quad = lane >> 4;
    const size_t nbase = (size_t)e * (DDIM * RDIM);
    const int k0 = oct * 128;

    for (int j = tid; j < cntE; j += 256) eL[j] = wsList[e * LCAP + j];

    {
        const int rq = tid & 15;
        const int kpB = tid >> 4;
        u32* bb = (u32*)Bb;
#pragma unroll
        for (int h = 0; h < 4; ++h) {
            int kp = kpB + h * 16;
            float4 g0 = nld.ld4(nbase + (size_t)(k0 + 2 * kp) * RDIM + rq * 4);
            float4 g1 = nld.ld4(nbase + (size_t)(k0 + 2 * kp + 1) * RDIM + rq * 4);
            bb[(rq * 4 + 0) * 68 + kp] = pack2(g0.x, g1.x);
            bb[(rq * 4 + 1) * 68 + kp] = pack2(g0.y, g1.y);
            bb[(rq * 4 + 2) * 68 + kp] = pack2(g0.z, g1.z);
            bb[(rq * 4 + 3) * 68 + kp] = pack2(g0.w, g1.w);
        }
    }
    __syncthreads();                              // Bb + eL visible

    const int rowA = tid >> 4;
    const int kqA = tid & 15;
    const int ntiles = (cntE + 15) >> 4;

    float4 c0, c1, n0, n1;
    {
        int t2r = eL[min(rowA, cntE - 1)];
        size_t xrow = (size_t)(t2r >> 1) * DDIM + k0;
        c0 = xld.ld4(xrow + kqA * 8);
        c1 = xld.ld4(xrow + kqA * 8 + 4);
    }
    n0 = c0; n1 = c1;
    if (ntiles > 1) {
        int t2r = eL[min(16 + rowA, cntE - 1)];
        size_t xrow = (size_t)(t2r >> 1) * DDIM + k0;
        n0 = xld.ld4(xrow + kqA * 8);
        n1 = xld.ld4(xrow + kqA * 8 + 4);
    }

    for (int ti = 0; ti < ntiles; ++ti) {
        const int base = ti * 16;
        const int valid = min(16, cntE - base);
        if (ti > 0) __syncthreads();
        {
            uint4 w;
            w.x = pack2(c0.x, c0.y);
            w.y = pack2(c0.z, c0.w);
            w.z = pack2(c1.x, c1.y);
            w.w = pack2(c1.z, c1.w);
            *(uint4*)&((u32*)Ab)[rowA * 68 + kqA * 4] = w;
        }
        __syncthreads();
        if (ti + 2 < ntiles) {
            int t2r = eL[min(base + 32 + rowA, cntE - 1)];
            size_t xrow = (size_t)(t2r >> 1) * DDIM + k0;
            c0 = xld.ld4(xrow + kqA * 8);
            c1 = xld.ld4(xrow + kqA * 8 + 4);
        }

        f32x4 acc = {0.f, 0.f, 0.f, 0.f};
#pragma unroll
        for (int ko = 0; ko < 4; ++ko) {
            int kofs = ko * 32 + quad * 8;
            short8 bfr = *(const short8*)&Bb[(16 * wv + l15) * 136 + kofs];
            short8 af = *(const short8*)&Ab[l15 * 136 + kofs];
            acc = __builtin_amdgcn_mfma_f32_16x16x32_bf16(af, bfr, acc, 0, 0, 0);
        }

#pragma unroll
        for (int reg = 0; reg < 4; ++reg) {
            int m = quad * 4 + reg;
            if (m < valid) {
                int t2 = eL[base + m];
                P[(size_t)t2 * 512 + oct * 64 + 16 * wv + l15] = acc[reg];
            }
        }

        float4 s0 = c0, s1 = c1;
        c0 = n0; c1 = n1;
        n0 = s0; n1 = s1;
    }
}

__global__ __launch_bounds__(256, 2) void expert_gemm(const void* x, const void* neurons,
                                                      const int* wsCnt, const int* wsList,
                                                      float* P) {
    __shared__ u16 Ab[16 * 136];
    __shared__ u16 Bb[64 * 136];
    __shared__ int eL[LCAP];
    __shared__ int dc;
    int f = detect_f32((const u16*)x, &dc);
    if (f)
        egemm_body(LdF32{(const float*)x}, LdF32{(const float*)neurons}, wsCnt, wsList, P, Ab, Bb, eL);
    else
        egemm_body(LdBF{(const u16*)x}, LdBF{(const u16*)neurons}, wsCnt, wsList, P, Ab, Bb, eL);
}

// ---------------- Kernel C: combine partials -------------------------------
// out[t][r] = sum_s wsW[2t+s] * sum_oct P[(2t+s)*512 + oct*64 + r].
// 1024 blocks x 256 thr; 1 element/thread; fully coalesced 256B segments.
__global__ __launch_bounds__(256) void combine(const float* P, const float* wsW,
                                               float* out) {
    int i = blockIdx.x * 256 + threadIdx.x;      // [0, 262144)
    int t = i >> 6, r = i & 63;
    const float* p0 = P + (size_t)(2 * t) * 512 + r;
    const float* p1 = P + (size_t)(2 * t + 1) * 512 + r;
    float s0 = 0.f, s1 = 0.f;
#pragma unroll
    for (int o = 0; o < 8; ++o) {
        s0 += p0[o * 64];
        s1 += p1[o * 64];
    }
    out[i] = wsW[2 * t] * s0 + wsW[2 * t + 1] * s1;
}

extern "C" void kernel_launch(void* const* d_in, const int* in_sizes, int n_in,
                              void* d_out, int out_size, void* d_ws, size_t ws_size,
                              hipStream_t stream) {
    const void* x = d_in[0];
    const void* rw = d_in[1];
    const void* neurons = d_in[2];
    float* out = (float*)d_out;

    char* wsc = (char*)d_ws;
    float* wsW = (float*)wsc;                                  // 32 KB
    int* wsCnt = (int*)(wsc + 32 * 1024);                      // 256 B
    int* wsList = (int*)(wsc + 32 * 1024 + 256);               // 256 KB
    float* Sb = (float*)(wsc + (1 << 20));                     // 2 MB @ +1MB
    float* P = (float*)(wsc + (4 << 20));                      // 16 MB @ +4MB

    hipMemsetAsync(wsCnt, 0, 256, stream);
    score_part<<<1024, 256, 0, stream>>>(x, rw, Sb);
    topk_softmax<<<64, 64, 0, stream>>>(Sb, out, wsW, wsCnt, wsList);
    expert_gemm<<<512, 256, 0, stream>>>(x, neurons, wsCnt, wsList, P);
    combine<<<1024, 256, 0, stream>>>(P, wsW, out);
}

// Round 14
// 123.340 us; speedup vs baseline: 2.6744x; 2.6744x over previous
//
#include <hip/hip_runtime.h>
#include <hip/hip_bf16.h>

// B=2,S=2048 -> T=4096 tokens; D=1024; N=64 experts; R=64; TOP_K=2.
// Inputs runtime-detected f32 vs bf16 (measured: f32). Outputs f32 flat:
// [0,262144) proj; [262144,270336) idx; [270336,278528) w.
// R23: R22's raw-barrier pipeline regressed 2.7x (WRITE_SIZE 397MB: the
// asm "memory" clobber + conditional parity regs demoted staging float4s
// to scratch). LESSON: asm memory clobbers poison regalloc in pipelined
// loops. After 9 failed score levers (occupancy x2, K-split x2, intensity,
// reg-pipeline x2, persistent-rw, fences, raw barriers) score's ~43us is
// this structure's floor. This round: revert EXACTLY to the 123.9us build
// (K-split score / 64x64 topk / 2-deep egemm / combine) with one zero-risk
// win: drop the 256B hipMemsetAsync dispatch -- score_part block 0 zeroes
// wsCnt (all score blocks finish before topk launches, stream-ordered).
// Harness d_ws poison fill (~44us, evicts L3 every iter) untouchable.
// d_ws: f32 w[8192] (32KB); int cnt[64]; int list[64*1024] (256KB);
//       Sb f32[2][4096][64] @ +1MB (2MB); P f32[8192][8][64] @ +4MB (16MB).

typedef unsigned short u16;
typedef unsigned int u32;
typedef __attribute__((ext_vector_type(8))) short short8;
typedef __attribute__((ext_vector_type(4))) float f32x4;

__device__ __forceinline__ float bf2f(u16 u) {
    u32 v = ((u32)u) << 16; float f; __builtin_memcpy(&f, &v, 4); return f;
}
__device__ __forceinline__ u16 f2bf(float f) {  // RNE
    u32 u; __builtin_memcpy(&u, &f, 4);
    u32 r = u + 0x7fff + ((u >> 16) & 1);
    return (u16)(r >> 16);
}
__device__ __forceinline__ u32 pack2(float a, float b) {
    return ((u32)f2bf(b) << 16) | (u32)f2bf(a);
}

#define T_TOKENS 4096
#define DDIM 1024
#define NEXP 64
#define RDIM 64
#define LCAP 1024
#define OUT_IDX_OFF 262144
#define OUT_W_OFF 270336

struct LdBF {
    const u16* p;
    __device__ __forceinline__ float4 ld4(size_t i) const {
        ushort4 v = *(const ushort4*)(p + i);
        return make_float4(bf2f(v.x), bf2f(v.y), bf2f(v.z), bf2f(v.w));
    }
    __device__ __forceinline__ float ld1(size_t i) const { return bf2f(p[i]); }
};
struct LdF32 {
    const float* p;
    __device__ __forceinline__ float4 ld4(size_t i) const { return *(const float4*)(p + i); }
    __device__ __forceinline__ float ld1(size_t i) const { return p[i]; }
};

// in-block dtype probe: 1 if f32, 0 if bf16 (all blocks same verdict).
__device__ __forceinline__ int detect_f32(const u16* x, int* lds_cnt) {
    if (threadIdx.x == 0) *lds_cnt = 0;
    __syncthreads();
    if (threadIdx.x < 256) {
        unsigned e = (x[threadIdx.x] >> 7) & 0xFF;
        if (e >= 0x68 && e <= 0x88) atomicAdd(lds_cnt, 1);
    }
    __syncthreads();
    int f = (*lds_cnt < 200) ? 1 : 0;
    __syncthreads();
    return f;
}

// ---------------- Kernel A: score GEMM partials (K-split) ------------------
// 1024 blocks x 256 thr: g=bid>>1 (tokens [8g,8g+8)), kh=bid&1 (k half
// [512kh,512kh+512)). 8 K-chunks of 64, order rotated by bid&7. R14-proven
// compute core (M4xE8 per-thread tile, 1-deep register prefetch, 60 VGPR).
// Partial scores written to Sb[kh*4096 + t][e]; top2 in its own kernel.
// Block 0 zeroes wsCnt (replaces the hipMemsetAsync dispatch; all score
// blocks complete before topk launches -- stream-ordered).
template <class LD>
__device__ __forceinline__ void score_body(LD xld, LD rwld,
                                           float* xs /*8*68*/, float* wt /*64*68*/,
                                           float* sc /*8*65*/, float* Sb) {
    const int tid = threadIdx.x;
    const int g = blockIdx.x >> 1;
    const int kh = blockIdx.x & 1;
    const size_t t0 = (size_t)g * 8;
    const int kbase = kh * 512;
    const int wv = tid >> 6;
    const int lane = tid & 63;
    const int tg = lane & 1;
    const int eg = (lane >> 1) & 7;
    const int kql = (lane >> 4) & 3;
    const int dd = 4 * kql + 16 * wv;
    const int kc0 = blockIdx.x & 7;    // rotated chunk start (8 chunks)

    const int sm = tid >> 4;            // staging roles (coalesced)
    const int sd4 = (tid & 15) * 4;

    float acc[4][8];
#pragma unroll
    for (int mi = 0; mi < 4; ++mi)
#pragma unroll
        for (int ei = 0; ei < 8; ++ei) acc[mi][ei] = 0.f;

    float4 px;
    if (tid < 128) px = xld.ld4((t0 + sm) * DDIM + kbase + kc0 * 64 + sd4);
    float4 pw[4];
#pragma unroll
    for (int h = 0; h < 4; ++h) {
        int i4 = tid + h * 256;
        pw[h] = rwld.ld4((size_t)(i4 >> 4) * DDIM + kbase + kc0 * 64 + (i4 & 15) * 4);
    }

    for (int i = 0; i < 8; ++i) {
        if (i > 0) __syncthreads();
        if (tid < 128) *(float4*)&xs[sm * 68 + sd4] = px;
#pragma unroll
        for (int h = 0; h < 4; ++h) {
            int i4 = tid + h * 256;
            *(float4*)&wt[(i4 >> 4) * 68 + (i4 & 15) * 4] = pw[h];
        }
        __syncthreads();

        if (i < 7) {
            int kn = kbase + ((i + 1 + kc0) & 7) * 64;
            if (tid < 128) px = xld.ld4((t0 + sm) * DDIM + kn + sd4);
#pragma unroll
            for (int h = 0; h < 4; ++h) {
                int i4 = tid + h * 256;
                pw[h] = rwld.ld4((size_t)(i4 >> 4) * DDIM + kn + (i4 & 15) * 4);
            }
        }

        float4 xv[4], wv4[8];
#pragma unroll
        for (int mi = 0; mi < 4; ++mi)
            xv[mi] = *(const float4*)&xs[(tg + 2 * mi) * 68 + dd];
#pragma unroll
        for (int ei = 0; ei < 8; ++ei)
            wv4[ei] = *(const float4*)&wt[(eg + 8 * ei) * 68 + dd];
#pragma unroll
        for (int mi = 0; mi < 4; ++mi)
#pragma unroll
            for (int ei = 0; ei < 8; ++ei)
                acc[mi][ei] += xv[mi].x * wv4[ei].x + xv[mi].y * wv4[ei].y +
                               xv[mi].z * wv4[ei].z + xv[mi].w * wv4[ei].w;
    }

    // in-wave k-quad reduce (deterministic tree over kql)
#pragma unroll
    for (int mi = 0; mi < 4; ++mi)
#pragma unroll
        for (int ei = 0; ei < 8; ++ei) {
            float v = acc[mi][ei];
            v += __shfl_xor(v, 16, 64);
            v += __shfl_xor(v, 32, 64);
            acc[mi][ei] = v;
        }
    __syncthreads();

    // cross-wave reduce: sequential wave phases (deterministic order)
    for (int w = 0; w < 4; ++w) {
        if (wv == w && kql == 0) {
#pragma unroll
            for (int mi = 0; mi < 4; ++mi)
#pragma unroll
                for (int ei = 0; ei < 8; ++ei) {
                    int idx = (tg + 2 * mi) * 65 + eg + 8 * ei;
                    sc[idx] = (w == 0) ? acc[mi][ei] : sc[idx] + acc[mi][ei];
                }
        }
        __syncthreads();
    }

    // store this K-half's partial scores: 8 tokens x 64 experts
    if (tid < 128) {
        int t = tid >> 4, e4 = (tid & 15) * 4;
        const float* s = &sc[t * 65 + e4];
        float4 v = make_float4(s[0], s[1], s[2], s[3]);
        *(float4*)&Sb[((size_t)kh * T_TOKENS + t0 + t) * 64 + e4] = v;
    }
}

__global__ __launch_bounds__(256, 4) void score_part(const void* x, const void* rw,
                                                     float* Sb, int* wsCnt) {
    __shared__ float xs[8 * 68];
    __shared__ float wt[64 * 68];
    __shared__ float sc[8 * 65];
    __shared__ int dc;
    if (blockIdx.x == 0 && threadIdx.x < NEXP) wsCnt[threadIdx.x] = 0;
    int f = detect_f32((const u16*)x, &dc);
    if (f)
        score_body(LdF32{(const float*)x}, LdF32{(const float*)rw}, xs, wt, sc, Sb);
    else
        score_body(LdBF{(const u16*)x}, LdBF{(const u16*)rw}, xs, wt, sc, Sb);
}

// ---------------- Kernel A2: top-2 + softmax + outputs + expert lists -----
// 64 blocks x 64 thr; 1 token/thread. score[t][e] = Sb[0][t][e]+Sb[1][t][e]
// (2-addend fl-sum: order-independent => deterministic). Same scan/tie-break
// semantics as reference (strict >, ascending j).
__global__ __launch_bounds__(64) void topk_softmax(const float* Sb, float* out,
                                                   float* wsW, int* wsCnt,
                                                   int* wsList) {
    int t = blockIdx.x * 64 + threadIdx.x;       // [0, 4096)
    const float* s0 = Sb + (size_t)t * 64;
    const float* s1 = Sb + ((size_t)T_TOKENS + t) * 64;
    float best = -1e30f, secv = -1e30f;
    int bi = 0, si = 0;
    for (int j = 0; j < NEXP; j += 4) {
        float4 a = *(const float4*)(s0 + j);
        float4 b = *(const float4*)(s1 + j);
        float v0 = a.x + b.x, v1 = a.y + b.y, v2 = a.z + b.z, v3 = a.w + b.w;
        if (v0 > best) { secv = best; si = bi; best = v0; bi = j; }
        else if (v0 > secv) { secv = v0; si = j; }
        if (v1 > best) { secv = best; si = bi; best = v1; bi = j + 1; }
        else if (v1 > secv) { secv = v1; si = j + 1; }
        if (v2 > best) { secv = best; si = bi; best = v2; bi = j + 2; }
        else if (v2 > secv) { secv = v2; si = j + 2; }
        if (v3 > best) { secv = best; si = bi; best = v3; bi = j + 3; }
        else if (v3 > secv) { secv = v3; si = j + 3; }
    }
    float w0 = 1.0f / (1.0f + expf(secv - best));
    float w1 = 1.0f - w0;
    out[OUT_IDX_OFF + (size_t)t * 2 + 0] = (float)bi;
    out[OUT_IDX_OFF + (size_t)t * 2 + 1] = (float)si;
    out[OUT_W_OFF + (size_t)t * 2 + 0] = w0;
    out[OUT_W_OFF + (size_t)t * 2 + 1] = w1;
    wsW[t * 2 + 0] = w0;
    wsW[t * 2 + 1] = w1;
    int p0 = atomicAdd(&wsCnt[bi], 1);
    if (p0 < LCAP) wsList[bi * LCAP + p0] = t * 2 + 0;
    int p1 = atomicAdd(&wsCnt[si], 1);
    if (p1 < LCAP) wsList[si * LCAP + p1] = t * 2 + 1;
}

// ---------------- Kernel B: per-expert bf16 MFMA GEMM, K-eighth persist-B --
// 512 blocks: e = bid>>3, oct = bid&7; k window [oct*128, oct*128+128).
// Stage B eighth ONCE; preload expert token list to LDS. Tile loop:
// 2-deep A-prefetch (named reg sets + swap), 4 MFMA, plain stores of raw
// partials to P[t2*512 + oct*64 + col]. No atomics.
template <class LD>
__device__ __forceinline__ void egemm_body(LD xld, LD nld,
                                           const int* wsCnt, const int* wsList,
                                           float* P,
                                           u16* Ab /*16*136*/, u16* Bb /*64*136*/,
                                           int* eL /*1024*/) {
    const int tid = threadIdx.x;
    const int e = blockIdx.x >> 3;
    const int oct = blockIdx.x & 7;
    const int cntE = min(wsCnt[e], LCAP);
    if (cntE <= 0) return;                       // uniform exit
    const int wv = tid >> 6;
    const int lane = tid & 63;
    const int l15 = lane & 15, quad = lane >> 4;
    const size_t nbase = (size_t)e * (DDIM * RDIM);
    const int k0 = oct * 128;

    for (int j = tid; j < cntE; j += 256) eL[j] = wsList[e * LCAP + j];

    {
        const int rq = tid & 15;
        const int kpB = tid >> 4;
        u32* bb = (u32*)Bb;
#pragma unroll
        for (int h = 0; h < 4; ++h) {
            int kp = kpB + h * 16;
            float4 g0 = nld.ld4(nbase + (size_t)(k0 + 2 * kp) * RDIM + rq * 4);
            float4 g1 = nld.ld4(nbase + (size_t)(k0 + 2 * kp + 1) * RDIM + rq * 4);
            bb[(rq * 4 + 0) * 68 + kp] = pack2(g0.x, g1.x);
            bb[(rq * 4 + 1) * 68 + kp] = pack2(g0.y, g1.y);
            bb[(rq * 4 + 2) * 68 + kp] = pack2(g0.z, g1.z);
            bb[(rq * 4 + 3) * 68 + kp] = pack2(g0.w, g1.w);
        }
    }
    __syncthreads();                              // Bb + eL visible

    const int rowA = tid >> 4;
    const int kqA = tid & 15;
    const int ntiles = (cntE + 15) >> 4;

    float4 c0, c1, n0, n1;
    {
        int t2r = eL[min(rowA, cntE - 1)];
        size_t xrow = (size_t)(t2r >> 1) * DDIM + k0;
        c0 = xld.ld4(xrow + kqA * 8);
        c1 = xld.ld4(xrow + kqA * 8 + 4);
    }
    n0 = c0; n1 = c1;
    if (ntiles > 1) {
        int t2r = eL[min(16 + rowA, cntE - 1)];
        size_t xrow = (size_t)(t2r >> 1) * DDIM + k0;
        n0 = xld.ld4(xrow + kqA * 8);
        n1 = xld.ld4(xrow + kqA * 8 + 4);
    }

    for (int ti = 0; ti < ntiles; ++ti) {
        const int base = ti * 16;
        const int valid = min(16, cntE - base);
        if (ti > 0) __syncthreads();
        {
            uint4 w;
            w.x = pack2(c0.x, c0.y);
            w.y = pack2(c0.z, c0.w);
            w.z = pack2(c1.x, c1.y);
            w.w = pack2(c1.z, c1.w);
            *(uint4*)&((u32*)Ab)[rowA * 68 + kqA * 4] = w;
        }
        __syncthreads();
        if (ti + 2 < ntiles) {
            int t2r = eL[min(base + 32 + rowA, cntE - 1)];
            size_t xrow = (size_t)(t2r >> 1) * DDIM + k0;
            c0 = xld.ld4(xrow + kqA * 8);
            c1 = xld.ld4(xrow + kqA * 8 + 4);
        }

        f32x4 acc = {0.f, 0.f, 0.f, 0.f};
#pragma unroll
        for (int ko = 0; ko < 4; ++ko) {
            int kofs = ko * 32 + quad * 8;
            short8 bfr = *(const short8*)&Bb[(16 * wv + l15) * 136 + kofs];
            short8 af = *(const short8*)&Ab[l15 * 136 + kofs];
            acc = __builtin_amdgcn_mfma_f32_16x16x32_bf16(af, bfr, acc, 0, 0, 0);
        }

#pragma unroll
        for (int reg = 0; reg < 4; ++reg) {
            int m = quad * 4 + reg;
            if (m < valid) {
                int t2 = eL[base + m];
                P[(size_t)t2 * 512 + oct * 64 + 16 * wv + l15] = acc[reg];
            }
        }

        float4 s0 = c0, s1 = c1;
        c0 = n0; c1 = n1;
        n0 = s0; n1 = s1;
    }
}

__global__ __launch_bounds__(256, 2) void expert_gemm(const void* x, const void* neurons,
                                                      const int* wsCnt, const int* wsList,
                                                      float* P) {
    __shared__ u16 Ab[16 * 136];
    __shared__ u16 Bb[64 * 136];
    __shared__ int eL[LCAP];
    __shared__ int dc;
    int f = detect_f32((const u16*)x, &dc);
    if (f)
        egemm_body(LdF32{(const float*)x}, LdF32{(const float*)neurons}, wsCnt, wsList, P, Ab, Bb, eL);
    else
        egemm_body(LdBF{(const u16*)x}, LdBF{(const u16*)neurons}, wsCnt, wsList, P, Ab, Bb, eL);
}

// ---------------- Kernel C: combine partials -------------------------------
// out[t][r] = sum_s wsW[2t+s] * sum_oct P[(2t+s)*512 + oct*64 + r].
// 1024 blocks x 256 thr; 1 element/thread; fully coalesced 256B segments.
__global__ __launch_bounds__(256) void combine(const float* P, const float* wsW,
                                               float* out) {
    int i = blockIdx.x * 256 + threadIdx.x;      // [0, 262144)
    int t = i >> 6, r = i & 63;
    const float* p0 = P + (size_t)(2 * t) * 512 + r;
    const float* p1 = P + (size_t)(2 * t + 1) * 512 + r;
    float s0 = 0.f, s1 = 0.f;
#pragma unroll
    for (int o = 0; o < 8; ++o) {
        s0 += p0[o * 64];
        s1 += p1[o * 64];
    }
    out[i] = wsW[2 * t] * s0 + wsW[2 * t + 1] * s1;
}

extern "C" void kernel_launch(void* const* d_in, const int* in_sizes, int n_in,
                              void* d_out, int out_size, void* d_ws, size_t ws_size,
                              hipStream_t stream) {
    const void* x = d_in[0];
    const void* rw = d_in[1];
    const void* neurons = d_in[2];
    float* out = (float*)d_out;

    char* wsc = (char*)d_ws;
    float* wsW = (float*)wsc;                                  // 32 KB
    int* wsCnt = (int*)(wsc + 32 * 1024);                      // 256 B
    int* wsList = (int*)(wsc + 32 * 1024 + 256);               // 256 KB
    float* Sb = (float*)(wsc + (1 << 20));                     // 2 MB @ +1MB
    float* P = (float*)(wsc + (4 << 20));                      // 16 MB @ +4MB

    score_part<<<1024, 256, 0, stream>>>(x, rw, Sb, wsCnt);
    topk_softmax<<<64, 64, 0, stream>>>(Sb, out, wsW, wsCnt, wsList);
    expert_gemm<<<512, 256, 0, stream>>>(x, neurons, wsCnt, wsList, P);
    combine<<<1024, 256, 0, stream>>>(P, wsW, out);
}

// Round 15
// 122.304 us; speedup vs baseline: 2.6971x; 1.0085x over previous
//
#include <hip/hip_runtime.h>
#include <hip/hip_bf16.h>

// B=2,S=2048 -> T=4096 tokens; D=1024; N=64 experts; R=64; TOP_K=2.
// Inputs runtime-detected f32 vs bf16 (measured: f32). Outputs f32 flat:
// [0,262144) proj; [262144,270336) idx; [270336,278528) w.
// R24: R23 banked 123.3 (memset fused into score block 0). Remaining terms:
// fill 44 (untouchable) + score 43 (9 levers exhausted -- floor) + tail 36.
// This round, one low-risk consolidation: score emits bf16(x) as a
// byproduct (each element converted ONCE by its owning (g,kh) block, same
// RNE pack2 egemm used -> bit-identical); egemm A-gather reads ushort8
// directly into Ab's packed-u32 layout (memory order matches). A-traffic
// 33.5->16.8MB, pack VALU removed from tile loop, prefetch regs halved.
// Cost: 1 coalesced 8B store/staging-thread/chunk in score (+8.4MB write).
// Everything else byte-identical to the 123.3 build.
// Harness d_ws poison fill (~44us, evicts L3 every iter) untouchable.
// d_ws: f32 w[8192] (32KB); int cnt[64]; int list[64*1024] (256KB);
//       Sb f32[2][4096][64] @+1MB (2MB); P f32[8192][8][64] @+4MB (16MB);
//       xbf u16[4096*1024] @+24MB (8.4MB).

typedef unsigned short u16;
typedef unsigned int u32;
typedef __attribute__((ext_vector_type(8))) short short8;
typedef __attribute__((ext_vector_type(4))) float f32x4;

__device__ __forceinline__ float bf2f(u16 u) {
    u32 v = ((u32)u) << 16; float f; __builtin_memcpy(&f, &v, 4); return f;
}
__device__ __forceinline__ u16 f2bf(float f) {  // RNE
    u32 u; __builtin_memcpy(&u, &f, 4);
    u32 r = u + 0x7fff + ((u >> 16) & 1);
    return (u16)(r >> 16);
}
__device__ __forceinline__ u32 pack2(float a, float b) {
    return ((u32)f2bf(b) << 16) | (u32)f2bf(a);
}

#define T_TOKENS 4096
#define DDIM 1024
#define NEXP 64
#define RDIM 64
#define LCAP 1024
#define OUT_IDX_OFF 262144
#define OUT_W_OFF 270336

struct LdBF {
    const u16* p;
    __device__ __forceinline__ float4 ld4(size_t i) const {
        ushort4 v = *(const ushort4*)(p + i);
        return make_float4(bf2f(v.x), bf2f(v.y), bf2f(v.z), bf2f(v.w));
    }
    __device__ __forceinline__ float ld1(size_t i) const { return bf2f(p[i]); }
};
struct LdF32 {
    const float* p;
    __device__ __forceinline__ float4 ld4(size_t i) const { return *(const float4*)(p + i); }
    __device__ __forceinline__ float ld1(size_t i) const { return p[i]; }
};

// in-block dtype probe: 1 if f32, 0 if bf16 (all blocks same verdict).
__device__ __forceinline__ int detect_f32(const u16* x, int* lds_cnt) {
    if (threadIdx.x == 0) *lds_cnt = 0;
    __syncthreads();
    if (threadIdx.x < 256) {
        unsigned e = (x[threadIdx.x] >> 7) & 0xFF;
        if (e >= 0x68 && e <= 0x88) atomicAdd(lds_cnt, 1);
    }
    __syncthreads();
    int f = (*lds_cnt < 200) ? 1 : 0;
    __syncthreads();
    return f;
}

// ---------------- Kernel A: score GEMM partials (K-split) ------------------
// 1024 blocks x 256 thr: g=bid>>1 (tokens [8g,8g+8)), kh=bid&1 (k half
// [512kh,512kh+512)). 8 K-chunks of 64, order rotated by bid&7. R14-proven
// compute core (M4xE8 per-thread tile, 1-deep register prefetch, 60 VGPR).
// Partial scores -> Sb[kh*4096 + t][e]; top2 in its own kernel.
// NEW: staging threads also emit bf16(px) to xbf (one 8B coalesced store
// per chunk; each x element converted exactly once chip-wide, same RNE as
// egemm's old inline pack2 -> bit-identical downstream).
// Block 0 zeroes wsCnt (replaces the hipMemsetAsync dispatch).
template <class LD>
__device__ __forceinline__ void score_body(LD xld, LD rwld,
                                           float* xs /*8*68*/, float* wt /*64*68*/,
                                           float* sc /*8*65*/, float* Sb, u16* xbf) {
    const int tid = threadIdx.x;
    const int g = blockIdx.x >> 1;
    const int kh = blockIdx.x & 1;
    const size_t t0 = (size_t)g * 8;
    const int kbase = kh * 512;
    const int wv = tid >> 6;
    const int lane = tid & 63;
    const int tg = lane & 1;
    const int eg = (lane >> 1) & 7;
    const int kql = (lane >> 4) & 3;
    const int dd = 4 * kql + 16 * wv;
    const int kc0 = blockIdx.x & 7;    // rotated chunk start (8 chunks)

    const int sm = tid >> 4;            // staging roles (coalesced)
    const int sd4 = (tid & 15) * 4;

    float acc[4][8];
#pragma unroll
    for (int mi = 0; mi < 4; ++mi)
#pragma unroll
        for (int ei = 0; ei < 8; ++ei) acc[mi][ei] = 0.f;

    float4 px;
    if (tid < 128) px = xld.ld4((t0 + sm) * DDIM + kbase + kc0 * 64 + sd4);
    float4 pw[4];
#pragma unroll
    for (int h = 0; h < 4; ++h) {
        int i4 = tid + h * 256;
        pw[h] = rwld.ld4((size_t)(i4 >> 4) * DDIM + kbase + kc0 * 64 + (i4 & 15) * 4);
    }

    for (int i = 0; i < 8; ++i) {
        if (i > 0) __syncthreads();
        if (tid < 128) {
            *(float4*)&xs[sm * 68 + sd4] = px;
            // bf16 byproduct: 4 floats -> 2 packed u32 (8B store, coalesced)
            int kchn = kbase + ((i + kc0) & 7) * 64;
            uint2 b;
            b.x = pack2(px.x, px.y);
            b.y = pack2(px.z, px.w);
            *(uint2*)&xbf[(t0 + sm) * DDIM + kchn + sd4] = b;
        }
#pragma unroll
        for (int h = 0; h < 4; ++h) {
            int i4 = tid + h * 256;
            *(float4*)&wt[(i4 >> 4) * 68 + (i4 & 15) * 4] = pw[h];
        }
        __syncthreads();

        if (i < 7) {
            int kn = kbase + ((i + 1 + kc0) & 7) * 64;
            if (tid < 128) px = xld.ld4((t0 + sm) * DDIM + kn + sd4);
#pragma unroll
            for (int h = 0; h < 4; ++h) {
                int i4 = tid + h * 256;
                pw[h] = rwld.ld4((size_t)(i4 >> 4) * DDIM + kn + (i4 & 15) * 4);
            }
        }

        float4 xv[4], wv4[8];
#pragma unroll
        for (int mi = 0; mi < 4; ++mi)
            xv[mi] = *(const float4*)&xs[(tg + 2 * mi) * 68 + dd];
#pragma unroll
        for (int ei = 0; ei < 8; ++ei)
            wv4[ei] = *(const float4*)&wt[(eg + 8 * ei) * 68 + dd];
#pragma unroll
        for (int mi = 0; mi < 4; ++mi)
#pragma unroll
            for (int ei = 0; ei < 8; ++ei)
                acc[mi][ei] += xv[mi].x * wv4[ei].x + xv[mi].y * wv4[ei].y +
                               xv[mi].z * wv4[ei].z + xv[mi].w * wv4[ei].w;
    }

    // in-wave k-quad reduce (deterministic tree over kql)
#pragma unroll
    for (int mi = 0; mi < 4; ++mi)
#pragma unroll
        for (int ei = 0; ei < 8; ++ei) {
            float v = acc[mi][ei];
            v += __shfl_xor(v, 16, 64);
            v += __shfl_xor(v, 32, 64);
            acc[mi][ei] = v;
        }
    __syncthreads();

    // cross-wave reduce: sequential wave phases (deterministic order)
    for (int w = 0; w < 4; ++w) {
        if (wv == w && kql == 0) {
#pragma unroll
            for (int mi = 0; mi < 4; ++mi)
#pragma unroll
                for (int ei = 0; ei < 8; ++ei) {
                    int idx = (tg + 2 * mi) * 65 + eg + 8 * ei;
                    sc[idx] = (w == 0) ? acc[mi][ei] : sc[idx] + acc[mi][ei];
                }
        }
        __syncthreads();
    }

    // store this K-half's partial scores: 8 tokens x 64 experts
    if (tid < 128) {
        int t = tid >> 4, e4 = (tid & 15) * 4;
        const float* s = &sc[t * 65 + e4];
        float4 v = make_float4(s[0], s[1], s[2], s[3]);
        *(float4*)&Sb[((size_t)kh * T_TOKENS + t0 + t) * 64 + e4] = v;
    }
}

__global__ __launch_bounds__(256, 4) void score_part(const void* x, const void* rw,
                                                     float* Sb, int* wsCnt, u16* xbf) {
    __shared__ float xs[8 * 68];
    __shared__ float wt[64 * 68];
    __shared__ float sc[8 * 65];
    __shared__ int dc;
    if (blockIdx.x == 0 && threadIdx.x < NEXP) wsCnt[threadIdx.x] = 0;
    int f = detect_f32((const u16*)x, &dc);
    if (f)
        score_body(LdF32{(const float*)x}, LdF32{(const float*)rw}, xs, wt, sc, Sb, xbf);
    else
        score_body(LdBF{(const u16*)x}, LdBF{(const u16*)rw}, xs, wt, sc, Sb, xbf);
}

// ---------------- Kernel A2: top-2 + softmax + outputs + expert lists -----
// 64 blocks x 64 thr; 1 token/thread. score[t][e] = Sb[0][t][e]+Sb[1][t][e]
// (2-addend fl-sum: order-independent => deterministic). Same scan/tie-break
// semantics as reference (strict >, ascending j).
__global__ __launch_bounds__(64) void topk_softmax(const float* Sb, float* out,
                                                   float* wsW, int* wsCnt,
                                                   int* wsList) {
    int t = blockIdx.x * 64 + threadIdx.x;       // [0, 4096)
    const float* s0 = Sb + (size_t)t * 64;
    const float* s1 = Sb + ((size_t)T_TOKENS + t) * 64;
    float best = -1e30f, secv = -1e30f;
    int bi = 0, si = 0;
    for (int j = 0; j < NEXP; j += 4) {
        float4 a = *(const float4*)(s0 + j);
        float4 b = *(const float4*)(s1 + j);
        float v0 = a.x + b.x, v1 = a.y + b.y, v2 = a.z + b.z, v3 = a.w + b.w;
        if (v0 > best) { secv = best; si = bi; best = v0; bi = j; }
        else if (v0 > secv) { secv = v0; si = j; }
        if (v1 > best) { secv = best; si = bi; best = v1; bi = j + 1; }
        else if (v1 > secv) { secv = v1; si = j + 1; }
        if (v2 > best) { secv = best; si = bi; best = v2; bi = j + 2; }
        else if (v2 > secv) { secv = v2; si = j + 2; }
        if (v3 > best) { secv = best; si = bi; best = v3; bi = j + 3; }
        else if (v3 > secv) { secv = v3; si = j + 3; }
    }
    float w0 = 1.0f / (1.0f + expf(secv - best));
    float w1 = 1.0f - w0;
    out[OUT_IDX_OFF + (size_t)t * 2 + 0] = (float)bi;
    out[OUT_IDX_OFF + (size_t)t * 2 + 1] = (float)si;
    out[OUT_W_OFF + (size_t)t * 2 + 0] = w0;
    out[OUT_W_OFF + (size_t)t * 2 + 1] = w1;
    wsW[t * 2 + 0] = w0;
    wsW[t * 2 + 1] = w1;
    int p0 = atomicAdd(&wsCnt[bi], 1);
    if (p0 < LCAP) wsList[bi * LCAP + p0] = t * 2 + 0;
    int p1 = atomicAdd(&wsCnt[si], 1);
    if (p1 < LCAP) wsList[si * LCAP + p1] = t * 2 + 1;
}

// ---------------- Kernel B: per-expert bf16 MFMA GEMM, K-eighth persist-B --
// 512 blocks: e = bid>>3, oct = bid&7; k window [oct*128, oct*128+128).
// Stage B eighth ONCE; preload expert token list to LDS. Tile loop:
// 2-deep A-prefetch (named reg sets + swap). A now read from xbf (bf16,
// written by score with identical RNE): one uint4 (16B) per thread per
// tile -- half the old f32 traffic, zero pack VALU (memory order of
// consecutive bf16 == Ab's packed-u32 layout). 4 MFMA, plain stores of
// raw partials to P[t2*512 + oct*64 + col]. No atomics.
template <class LD>
__device__ __forceinline__ void egemm_body(LD nld, const u16* xbf,
                                           const int* wsCnt, const int* wsList,
                                           float* P,
                                           u16* Ab /*16*136*/, u16* Bb /*64*136*/,
                                           int* eL /*1024*/) {
    const int tid = threadIdx.x;
    const int e = blockIdx.x >> 3;
    const int oct = blockIdx.x & 7;
    const int cntE = min(wsCnt[e], LCAP);
    if (cntE <= 0) return;                       // uniform exit
    const int wv = tid >> 6;
    const int lane = tid & 63;
    const int l15 = lane & 15, quad = lane >> 4;
    const size_t nbase = (size_t)e * (DDIM * RDIM);
    const int k0 = oct * 128;

    for (int j = tid; j < cntE; j += 256) eL[j] = wsList[e * LCAP + j];

    {
        const int rq = tid & 15;
        const int kpB = tid >> 4;
        u32* bb = (u32*)Bb;
#pragma unroll
        for (int h = 0; h < 4; ++h) {
            int kp = kpB + h * 16;
            float4 g0 = nld.ld4(nbase + (size_t)(k0 + 2 * kp) * RDIM + rq * 4);
            float4 g1 = nld.ld4(nbase + (size_t)(k0 + 2 * kp + 1) * RDIM + rq * 4);
            bb[(rq * 4 + 0) * 68 + kp] = pack2(g0.x, g1.x);
            bb[(rq * 4 + 1) * 68 + kp] = pack2(g0.y, g1.y);
            bb[(rq * 4 + 2) * 68 + kp] = pack2(g0.z, g1.z);
            bb[(rq * 4 + 3) * 68 + kp] = pack2(g0.w, g1.w);
        }
    }
    __syncthreads();                              // Bb + eL visible

    const int rowA = tid >> 4;
    const int kqA = tid & 15;
    const int ntiles = (cntE + 15) >> 4;

    // 2-deep A prefetch from xbf: one uint4 (8 bf16) per thread per tile.
    uint4 ca, na;
    {
        int t2r = eL[min(rowA, cntE - 1)];
        ca = *(const uint4*)&xbf[(size_t)(t2r >> 1) * DDIM + k0 + kqA * 8];
    }
    na = ca;
    if (ntiles > 1) {
        int t2r = eL[min(16 + rowA, cntE - 1)];
        na = *(const uint4*)&xbf[(size_t)(t2r >> 1) * DDIM + k0 + kqA * 8];
    }

    for (int ti = 0; ti < ntiles; ++ti) {
        const int base = ti * 16;
        const int valid = min(16, cntE - base);
        if (ti > 0) __syncthreads();
        *(uint4*)&((u32*)Ab)[rowA * 68 + kqA * 4] = ca;
        __syncthreads();
        if (ti + 2 < ntiles) {
            int t2r = eL[min(base + 32 + rowA, cntE - 1)];
            ca = *(const uint4*)&xbf[(size_t)(t2r >> 1) * DDIM + k0 + kqA * 8];
        }

        f32x4 acc = {0.f, 0.f, 0.f, 0.f};
#pragma unroll
        for (int ko = 0; ko < 4; ++ko) {
            int kofs = ko * 32 + quad * 8;
            short8 bfr = *(const short8*)&Bb[(16 * wv + l15) * 136 + kofs];
            short8 af = *(const short8*)&Ab[l15 * 136 + kofs];
            acc = __builtin_amdgcn_mfma_f32_16x16x32_bf16(af, bfr, acc, 0, 0, 0);
        }

#pragma unroll
        for (int reg = 0; reg < 4; ++reg) {
            int m = quad * 4 + reg;
            if (m < valid) {
                int t2 = eL[base + m];
                P[(size_t)t2 * 512 + oct * 64 + 16 * wv + l15] = acc[reg];
            }
        }

        uint4 s = ca;
        ca = na;
        na = s;
    }
}

__global__ __launch_bounds__(256, 2) void expert_gemm(const void* x, const void* neurons,
                                                      const u16* xbf,
                                                      const int* wsCnt, const int* wsList,
                                                      float* P) {
    __shared__ u16 Ab[16 * 136];
    __shared__ u16 Bb[64 * 136];
    __shared__ int eL[LCAP];
    __shared__ int dc;
    int f = detect_f32((const u16*)x, &dc);
    if (f)
        egemm_body(LdF32{(const float*)neurons}, xbf, wsCnt, wsList, P, Ab, Bb, eL);
    else
        egemm_body(LdBF{(const u16*)neurons}, xbf, wsCnt, wsList, P, Ab, Bb, eL);
}

// ---------------- Kernel C: combine partials -------------------------------
// out[t][r] = sum_s wsW[2t+s] * sum_oct P[(2t+s)*512 + oct*64 + r].
// 1024 blocks x 256 thr; 1 element/thread; fully coalesced 256B segments.
__global__ __launch_bounds__(256) void combine(const float* P, const float* wsW,
                                               float* out) {
    int i = blockIdx.x * 256 + threadIdx.x;      // [0, 262144)
    int t = i >> 6, r = i & 63;
    const float* p0 = P + (size_t)(2 * t) * 512 + r;
    const float* p1 = P + (size_t)(2 * t + 1) * 512 + r;
    float s0 = 0.f, s1 = 0.f;
#pragma unroll
    for (int o = 0; o < 8; ++o) {
        s0 += p0[o * 64];
        s1 += p1[o * 64];
    }
    out[i] = wsW[2 * t] * s0 + wsW[2 * t + 1] * s1;
}

extern "C" void kernel_launch(void* const* d_in, const int* in_sizes, int n_in,
                              void* d_out, int out_size, void* d_ws, size_t ws_size,
                              hipStream_t stream) {
    const void* x = d_in[0];
    const void* rw = d_in[1];
    const void* neurons = d_in[2];
    float* out = (float*)d_out;

    char* wsc = (char*)d_ws;
    float* wsW = (float*)wsc;                                  // 32 KB
    int* wsCnt = (int*)(wsc + 32 * 1024);                      // 256 B
    int* wsList = (int*)(wsc + 32 * 1024 + 256);               // 256 KB
    float* Sb = (float*)(wsc + (1 << 20));                     // 2 MB @ +1MB
    float* P = (float*)(wsc + (4 << 20));                      // 16 MB @ +4MB
    u16* xbf = (u16*)(wsc + (24 << 20));                       // 8.4 MB @ +24MB

    score_part<<<1024, 256, 0, stream>>>(x, rw, Sb, wsCnt, xbf);
    topk_softmax<<<64, 64, 0, stream>>>(Sb, out, wsW, wsCnt, wsList);
    expert_gemm<<<512, 256, 0, stream>>>(x, neurons, xbf, wsCnt, wsList, P);
    combine<<<1024, 256, 0, stream>>>(P, wsW, out);
}